// Round 3
// baseline (128.951 us; speedup 1.0000x reference)
//
#include <hip/hip_runtime.h>
#include <math.h>

#define NEGV (-9e15f)
#define SLOPE 0.2f
#define ITILE 10     // i-rows per block
#define STW   12     // ST row width (ITILE padded to float4 multiple)

// Grid: 32 b x 20 i-tiles = 640 blocks; block covers i = i0 .. i0+9. 256 threads.
// LDS ~26.5 KB -> ~3 blocks/CU (VGPR-bound), 12 waves/CU.
__global__ __launch_bounds__(256) void gat_tile_kernel(
    const int*   __restrict__ inputs,   // [32,200]
    const int*   __restrict__ adj,      // [32,200,200]
    const float* __restrict__ emb,      // [V,100]
    const float* __restrict__ a0, const float* __restrict__ a1,
    const float* __restrict__ a2, const float* __restrict__ a3,
    float*       __restrict__ out)      // [32,200,100]
{
    const int b   = blockIdx.x / 20;
    const int i0  = (blockIdx.x % 20) * ITILE;
    const int tid = threadIdx.x;

    __shared__ int   sidx[200];          // emb row per session position
    __shared__ float G[ITILE][4][100];   // h_{i0+i} * a_k   (16 KB)
    __shared__ float ST[200][STW];       // scores/weights [j][i] (9.6 KB)

    if (tid < 200) sidx[tid] = inputs[b * 200 + tid];
    __syncthreads();

    const float4* embv = (const float4*)emb;

    // ---- Register loads first (h_j rows + adj column), then G fill ----
    float4 h[25];
    int    kv[ITILE];
    if (tid < 200) {
        const size_t hb = (size_t)sidx[tid] * 25;
        #pragma unroll
        for (int c = 0; c < 25; ++c) h[c] = embv[hb + c];
        const int arow = (b * 200 + i0) * 200 + tid;
        #pragma unroll
        for (int i = 0; i < ITILE; ++i) kv[i] = adj[arow + i * 200];
    }

    // G[i][k][:] = emb[sidx[i0+i]] * a_k   (250 work items)
    if (tid < ITILE * 25) {
        const int i = tid / 25, dc = tid % 25;
        const float4 hv  = embv[(size_t)sidx[i0 + i] * 25 + dc];
        const float4 av0 = ((const float4*)a0)[dc];
        const float4 av1 = ((const float4*)a1)[dc];
        const float4 av2 = ((const float4*)a2)[dc];
        const float4 av3 = ((const float4*)a3)[dc];
        float4 g;
        g.x=hv.x*av0.x; g.y=hv.y*av0.y; g.z=hv.z*av0.z; g.w=hv.w*av0.w;
        ((float4*)&G[i][0][0])[dc] = g;
        g.x=hv.x*av1.x; g.y=hv.y*av1.y; g.z=hv.z*av1.z; g.w=hv.w*av1.w;
        ((float4*)&G[i][1][0])[dc] = g;
        g.x=hv.x*av2.x; g.y=hv.y*av2.y; g.z=hv.z*av2.z; g.w=hv.w*av2.w;
        ((float4*)&G[i][2][0])[dc] = g;
        g.x=hv.x*av3.x; g.y=hv.y*av3.y; g.z=hv.z*av3.z; g.w=hv.w*av3.w;
        ((float4*)&G[i][3][0])[dc] = g;
    }
    __syncthreads();   // G ready

    // ---- Score pass: thread j computes selected-k score vs each of ITILE i ----
    if (tid < 200) {
        #pragma unroll
        for (int i = 0; i < ITILE; ++i) {
            const int k  = kv[i];
            const int kk = (k - 1) & 3;            // any valid row when k==0
            const float4* Gv = (const float4*)&G[i][kk][0];
            float ax = 0.f, ay = 0.f, az = 0.f, aw = 0.f;
            #pragma unroll
            for (int c = 0; c < 25; ++c) {
                const float4 gv = Gv[c];
                ax += gv.x * h[c].x; ay += gv.y * h[c].y;
                az += gv.z * h[c].z; aw += gv.w * h[c].w;
            }
            float s = (ax + ay) + (az + aw);
            s = (s >= 0.f) ? s : SLOPE * s;
            ST[tid][i] = (k >= 1 && k <= 4) ? s : NEGV;
        }
    }
    __syncthreads();

    // ---- Softmax per i-row: 8 lanes per row (rows = ITILE) ----
    {
        const int r = tid >> 3, l = tid & 7;
        if (r < ITILE) {
            float m = -INFINITY;
            #pragma unroll
            for (int t = 0; t < 25; ++t) m = fmaxf(m, ST[l + 8 * t][r]);
            #pragma unroll
            for (int off = 4; off >= 1; off >>= 1) m = fmaxf(m, __shfl_xor(m, off, 8));
            float e[25];
            float sum = 0.f;
            #pragma unroll
            for (int t = 0; t < 25; ++t) {
                e[t] = __expf(ST[l + 8 * t][r] - m);
                sum += e[t];
            }
            #pragma unroll
            for (int off = 4; off >= 1; off >>= 1) sum += __shfl_xor(sum, off, 8);
            const float inv = 1.0f / sum;
            #pragma unroll
            for (int t = 0; t < 25; ++t) ST[l + 8 * t][r] = e[t] * inv;
        }
    }
    __syncthreads();

    // ---- Aggregation: thread (ig = tid&7, dc = tid>>3) -> j-segment ig, d-chunk dc ----
    {
        const int ig = tid & 7;
        const int dc = tid >> 3;                   // 0..31, active < 25
        float4 acc[ITILE];
        #pragma unroll
        for (int i = 0; i < ITILE; ++i) { acc[i].x=0.f; acc[i].y=0.f; acc[i].z=0.f; acc[i].w=0.f; }
        if (dc < 25) {
            for (int jj = 0; jj < 25; ++jj) {
                const int j = ig * 25 + jj;
                float4 w4[STW / 4];
                #pragma unroll
                for (int c = 0; c < STW / 4; ++c) w4[c] = ((const float4*)&ST[j][0])[c];
                const float* w = (const float*)w4;
                const float4 hv = embv[(size_t)sidx[j] * 25 + dc];
                #pragma unroll
                for (int i = 0; i < ITILE; ++i) {
                    acc[i].x += w[i] * hv.x; acc[i].y += w[i] * hv.y;
                    acc[i].z += w[i] * hv.z; acc[i].w += w[i] * hv.w;
                }
            }
        }
        #pragma unroll
        for (int i = 0; i < ITILE; ++i) {
            #pragma unroll
            for (int off = 1; off <= 4; off <<= 1) {
                acc[i].x += __shfl_xor(acc[i].x, off, 64);
                acc[i].y += __shfl_xor(acc[i].y, off, 64);
                acc[i].z += __shfl_xor(acc[i].z, off, 64);
                acc[i].w += __shfl_xor(acc[i].w, off, 64);
            }
        }
        if (ig == 0 && dc < 25) {
            #pragma unroll
            for (int i = 0; i < ITILE; ++i)
                ((float4*)out)[(size_t)(b * 200 + i0 + i) * 25 + dc] = acc[i];
        }
    }
}

extern "C" void kernel_launch(void* const* d_in, const int* in_sizes, int n_in,
                              void* d_out, int out_size, void* d_ws, size_t ws_size,
                              hipStream_t stream) {
    const int*   inputs = (const int*)  d_in[0];
    const int*   adj    = (const int*)  d_in[1];
    // d_in[2] = mask_item (all ones, unused)
    const float* emb    = (const float*)d_in[3];
    const float* a0     = (const float*)d_in[4];
    const float* a1     = (const float*)d_in[5];
    const float* a2     = (const float*)d_in[6];
    const float* a3     = (const float*)d_in[7];
    float*       out    = (float*)d_out;

    gat_tile_kernel<<<dim3(32 * 20), dim3(256), 0, stream>>>(inputs, adj, emb, a0, a1, a2, a3, out);
}

// Round 5
// 119.061 us; speedup vs baseline: 1.0831x; 1.0831x over previous
//
#include <hip/hip_runtime.h>
#include <math.h>

#define NEGV  (-9e15f)
#define SLOPE 0.2f
#define ITILE 10

typedef __fp16 h2 __attribute__((ext_vector_type(2)));

__device__ __forceinline__ h2 pk16(float x, float y) {
#if __has_builtin(__builtin_amdgcn_cvt_pkrtz)
    return __builtin_amdgcn_cvt_pkrtz(x, y);
#else
    h2 r; r.x = (__fp16)x; r.y = (__fp16)y; return r;
#endif
}

__device__ __forceinline__ float dot2acc(h2 a, h2 b, float c) {
#if __has_builtin(__builtin_amdgcn_fdot2)
    return __builtin_amdgcn_fdot2(a, b, c, false);
#else
    return c + (float)a.x * (float)b.x + (float)a.y * (float)b.y;
#endif
}

// ---------------- Kernel A: selected-k edge scores + softmax -> alpha ----------------
// Grid 640 = 32 b x 20 i-tiles(10). Block 256 (200 j-threads).
// G (h_i * a_k) packed fp16 in LDS (rows 208 B, 16B-aligned); h_j packed fp16 in regs.
__global__ __launch_bounds__(256) void score_kernel(
    const int*   __restrict__ inputs,
    const int*   __restrict__ adj,
    const float* __restrict__ emb,
    const float* __restrict__ a0, const float* __restrict__ a1,
    const float* __restrict__ a2, const float* __restrict__ a3,
    float*       __restrict__ alpha)      // [32,200,200]
{
    const int b   = blockIdx.x / 20;
    const int i0  = (blockIdx.x % 20) * ITILE;
    const int tid = threadIdx.x;

    __shared__ int sidx[200];
    __shared__ h2  G[ITILE][4][52];    // 104 halves/row (100 + 4 zero pad) = 208 B
    __shared__ float ST[200][13];      // stride 13: 2-way max on all patterns

    for (int t = tid; t < 200; t += 256) sidx[t] = inputs[b * 200 + t];
    __syncthreads();

    // ---- pack own h_j row into fp16 registers (52 VGPR) + adj column ----
    h2  hh[52];
    int kv[ITILE];
    if (tid < 200) {
        const float4* hv4 = (const float4*)(emb + (size_t)sidx[tid] * 100);
        #pragma unroll
        for (int c = 0; c < 25; ++c) {
            const float4 v = hv4[c];
            hh[2 * c]     = pk16(v.x, v.y);
            hh[2 * c + 1] = pk16(v.z, v.w);
        }
        hh[50] = pk16(0.f, 0.f);
        hh[51] = pk16(0.f, 0.f);
        const int arow = (b * 200 + i0) * 200 + tid;
        #pragma unroll
        for (int i = 0; i < ITILE; ++i) kv[i] = adj[arow + i * 200];
    }

    // ---- fill G: 10 i x 4 k x 52 h2 slots ----
    for (int t = tid; t < ITILE * 4 * 52; t += 256) {
        const int i = t / (4 * 52);
        const int r = t % (4 * 52);
        const int k = r / 52;
        const int s = r % 52;
        const int d0 = 2 * s, d1 = d0 + 1;
        const float* ak = (k == 0) ? a0 : (k == 1) ? a1 : (k == 2) ? a2 : a3;
        const float* hi = emb + (size_t)sidx[i0 + i] * 100;
        const float x = (d0 < 100) ? hi[d0] * ak[d0] : 0.f;
        const float y = (d1 < 100) ? hi[d1] * ak[d1] : 0.f;
        G[i][k][s] = pk16(x, y);
    }
    __syncthreads();

    // ---- score pass: thread j vs each of ITILE i, only the selected k ----
    if (tid < 200) {
        for (int i = 0; i < ITILE; ++i) {
            const int k = kv[i];
            const float4* Gv = (const float4*)&G[i][(k - 1) & 3][0];
            float s0 = 0.f, s1 = 0.f, s2 = 0.f, s3 = 0.f;
            #pragma unroll
            for (int c = 0; c < 13; ++c) {
                float4 g4 = Gv[c];
                const h2* g2 = (const h2*)&g4;
                s0 = dot2acc(g2[0], hh[4 * c + 0], s0);
                s1 = dot2acc(g2[1], hh[4 * c + 1], s1);
                s2 = dot2acc(g2[2], hh[4 * c + 2], s2);
                s3 = dot2acc(g2[3], hh[4 * c + 3], s3);
            }
            float s = (s0 + s1) + (s2 + s3);
            s = (s >= 0.f) ? s : SLOPE * s;
            ST[tid][i] = (k >= 1 && k <= 4) ? s : NEGV;
        }
    }
    __syncthreads();

    // ---- softmax per i-row (8 lanes/row), write alpha fp32 ----
    const int r = tid >> 3, l = tid & 7;
    if (r < ITILE) {
        float m = -INFINITY;
        #pragma unroll
        for (int t = 0; t < 25; ++t) m = fmaxf(m, ST[l + 8 * t][r]);
        #pragma unroll
        for (int off = 4; off >= 1; off >>= 1) m = fmaxf(m, __shfl_xor(m, off, 8));
        float e[25];
        float sum = 0.f;
        #pragma unroll
        for (int t = 0; t < 25; ++t) { e[t] = __expf(ST[l + 8 * t][r] - m); sum += e[t]; }
        #pragma unroll
        for (int off = 4; off >= 1; off >>= 1) sum += __shfl_xor(sum, off, 8);
        const float inv = 1.0f / sum;
        float* arow = alpha + (size_t)(b * 200 + i0 + r) * 200;
        #pragma unroll
        for (int t = 0; t < 25; ++t) arow[l + 8 * t] = e[t] * inv;
    }
}

// ---------------- Kernel B: out[b,i,:] = sum_j alpha[b,i,j] * h[b,j,:] ----------------
// Grid 640, block 256 = 8 j-segments x 32 d-chunks (25 active).
__global__ __launch_bounds__(256) void agg_kernel(
    const int*   __restrict__ inputs,
    const float* __restrict__ alpha,
    const float* __restrict__ emb,
    float*       __restrict__ out)
{
    const int b   = blockIdx.x / 20;
    const int i0  = (blockIdx.x % 20) * ITILE;
    const int tid = threadIdx.x;

    __shared__ int   sidx[200];
    __shared__ float WT[200][12];      // weights transposed [j][i], stride 12 (b128-clean)

    for (int t = tid; t < 200; t += 256) sidx[t] = inputs[b * 200 + t];
    const float* ab = alpha + (size_t)(b * 200 + i0) * 200;
    for (int t = tid; t < ITILE * 200; t += 256) {
        const int i = t / 200, j = t % 200;
        WT[j][i] = ab[i * 200 + j];    // coalesced global read
    }
    __syncthreads();

    const int ig = tid & 7;
    const int dc = tid >> 3;           // 0..31, active < 25
    float4 acc[ITILE];
    #pragma unroll
    for (int i = 0; i < ITILE; ++i) { acc[i].x = 0.f; acc[i].y = 0.f; acc[i].z = 0.f; acc[i].w = 0.f; }

    if (dc < 25) {
        const float4* embv = (const float4*)emb;
        for (int jj = 0; jj < 25; ++jj) {
            const int j = ig * 25 + jj;
            float4 w4[3];
            #pragma unroll
            for (int c = 0; c < 3; ++c) w4[c] = ((const float4*)&WT[j][0])[c];
            const float* w = (const float*)w4;
            const float4 hv = embv[(size_t)sidx[j] * 25 + dc];
            #pragma unroll
            for (int i = 0; i < ITILE; ++i) {
                acc[i].x += w[i] * hv.x; acc[i].y += w[i] * hv.y;
                acc[i].z += w[i] * hv.z; acc[i].w += w[i] * hv.w;
            }
        }
    }
    #pragma unroll
    for (int i = 0; i < ITILE; ++i) {
        #pragma unroll
        for (int off = 1; off <= 4; off <<= 1) {
            acc[i].x += __shfl_xor(acc[i].x, off, 64);
            acc[i].y += __shfl_xor(acc[i].y, off, 64);
            acc[i].z += __shfl_xor(acc[i].z, off, 64);
            acc[i].w += __shfl_xor(acc[i].w, off, 64);
        }
    }
    if (ig == 0 && dc < 25) {
        #pragma unroll
        for (int i = 0; i < ITILE; ++i)
            ((float4*)out)[(size_t)(b * 200 + i0 + i) * 25 + dc] = acc[i];
    }
}

extern "C" void kernel_launch(void* const* d_in, const int* in_sizes, int n_in,
                              void* d_out, int out_size, void* d_ws, size_t ws_size,
                              hipStream_t stream) {
    const int*   inputs = (const int*)  d_in[0];
    const int*   adj    = (const int*)  d_in[1];
    // d_in[2] = mask_item (all ones, unused)
    const float* emb    = (const float*)d_in[3];
    const float* a0     = (const float*)d_in[4];
    const float* a1     = (const float*)d_in[5];
    const float* a2     = (const float*)d_in[6];
    const float* a3     = (const float*)d_in[7];
    float*       out    = (float*)d_out;
    float*       alpha  = (float*)d_ws;            // 32*200*200*4 = 5.12 MB

    score_kernel<<<dim3(640), dim3(256), 0, stream>>>(inputs, adj, emb, a0, a1, a2, a3, alpha);
    agg_kernel  <<<dim3(640), dim3(256), 0, stream>>>(inputs, alpha, emb, out);
}

// Round 6
// 106.097 us; speedup vs baseline: 1.2154x; 1.1222x over previous
//
#include <hip/hip_runtime.h>
#include <math.h>

#define NEGV  (-9e15f)
#define SLOPE 0.2f

typedef __fp16 f16;
typedef __fp16 f16x4 __attribute__((ext_vector_type(4)));
typedef __fp16 f16x8 __attribute__((ext_vector_type(8)));
typedef float  f32x4 __attribute__((ext_vector_type(4)));

// One block per (b, 16-row i-tile). Grid 32*13=416, 256 threads (4 waves).
// Score via mfma_f32_16x16x32_f16 (all 4 k-planes), select-by-adj in C-layout,
// softmax with width-16 butterflies, scalar PV from LDS.
__global__ __launch_bounds__(256) void gat_mfma_kernel(
    const int*   __restrict__ inputs,   // [32,200]
    const int*   __restrict__ adj,      // [32,200,200]
    const float* __restrict__ emb,      // [V,100]
    const float* __restrict__ a0, const float* __restrict__ a1,
    const float* __restrict__ a2, const float* __restrict__ a3,
    float*       __restrict__ out)      // [32,200,100]
{
    const int b   = blockIdx.x / 13;
    const int i0  = (blockIdx.x % 13) * 16;
    const int tid = threadIdx.x;

    __shared__ f16 HF[200][112];              // h rows fp16, d 100..111 = 0 (44.8 KB)
    __shared__ __align__(16) unsigned char ubuf[4 * 16 * 96 * 2];  // GF / ST union (12.3 KB)
    __shared__ f16 GT[4][16][32];             // K-tail A-frags: d 80..95 zeroed, 96..99 real (4 KB)
    __shared__ int   sidx[200];
    __shared__ float redmax[16][4];
    __shared__ float redsum[16][4];

    f16 (*GF)[16][96] = (f16(*)[16][96])ubuf; // G[k][i][d] = h_i[d]*a_k[d], d<96
    f16 (*ST)[24]     = (f16(*)[24])ubuf;     // alpha[j][i] fp16 (9.6 KB, after GF dead)

    for (int t = tid; t < 200; t += 256) sidx[t] = inputs[b * 200 + t];
    __syncthreads();

    // ---- stage HF (one row per thread) ----
    if (tid < 200) {
        const float4* src = (const float4*)(emb + (size_t)sidx[tid] * 100);
        f16x4* dst = (f16x4*)&HF[tid][0];
        #pragma unroll
        for (int c = 0; c < 25; ++c) {
            const float4 v = src[c];
            f16x4 o; o[0] = (f16)v.x; o[1] = (f16)v.y; o[2] = (f16)v.z; o[3] = (f16)v.w;
            dst[c] = o;
        }
        const f16x4 z = {(f16)0.f, (f16)0.f, (f16)0.f, (f16)0.f};
        dst[25] = z; dst[26] = z; dst[27] = z;
    }

    // ---- stage GF: 4k x 16i x 24 f16x4 chunks (d<96) ----
    for (int t = tid; t < 4 * 16 * 24; t += 256) {
        const int kk = t / (16 * 24);
        const int rm = t % (16 * 24);
        const int il = rm / 24;
        const int c  = rm % 24;
        const float* ak = (kk == 0) ? a0 : (kk == 1) ? a1 : (kk == 2) ? a2 : a3;
        const int gi = i0 + il;
        f16x4 o = {(f16)0.f, (f16)0.f, (f16)0.f, (f16)0.f};
        if (gi < 200) {
            const float4 hv = ((const float4*)(emb + (size_t)sidx[gi] * 100))[c];
            const float4 av = ((const float4*)ak)[c];
            o[0] = (f16)(hv.x * av.x); o[1] = (f16)(hv.y * av.y);
            o[2] = (f16)(hv.z * av.z); o[3] = (f16)(hv.w * av.w);
        }
        ((f16x4*)&GF[kk][il][0])[c] = o;
    }

    // ---- stage GT: local d = 0..31 maps to global 80..111; only 96..99 (chunk 4) real ----
    for (int t = tid; t < 4 * 16 * 8; t += 256) {
        const int kk = t / (16 * 8);
        const int rm = t % (16 * 8);
        const int il = rm / 8;
        const int c  = rm % 8;
        f16x4 o = {(f16)0.f, (f16)0.f, (f16)0.f, (f16)0.f};
        const int gi = i0 + il;
        if (c == 4 && gi < 200) {
            const float* ak = (kk == 0) ? a0 : (kk == 1) ? a1 : (kk == 2) ? a2 : a3;
            const float* hi = emb + (size_t)sidx[gi] * 100;
            o[0] = (f16)(hi[96] * ak[96]); o[1] = (f16)(hi[97] * ak[97]);
            o[2] = (f16)(hi[98] * ak[98]); o[3] = (f16)(hi[99] * ak[99]);
        }
        ((f16x4*)&GT[kk][il][0])[c] = o;
    }
    __syncthreads();

    const int wave = tid >> 6;
    const int lane = tid & 63;
    const int lj   = lane & 15;        // col j within tile / A m-index
    const int quad = lane >> 4;
    const int rbase = quad * 4;

    // ---- score MFMAs: 16 j-tiles across 4 waves, 4 k-planes, 4 K-steps ----
    f32x4 acc[4][4];                    // [k][jtidx]
    #pragma unroll
    for (int kk = 0; kk < 4; ++kk)
        #pragma unroll
        for (int jt = 0; jt < 4; ++jt)
            acc[kk][jt] = (f32x4){0.f, 0.f, 0.f, 0.f};

    #pragma unroll
    for (int jtidx = 0; jtidx < 4; ++jtidx) {
        const int j  = (wave + 4 * jtidx) * 16 + lj;
        const int jr = (j < 200) ? j : 0;           // clamped rows masked later
        const f16x8* Brow = (const f16x8*)&HF[jr][0];
        const f16x8 b0 = Brow[quad];                 // d 0..31
        const f16x8 b1 = Brow[4 + quad];             // d 32..63
        const f16x8 b2 = Brow[8 + quad];             // d 64..95
        const f16x8 b3 = Brow[10 + quad];            // d 80..111 (tail; A zero on 80..95)
        #pragma unroll
        for (int kk = 0; kk < 4; ++kk) {
            const f16x8* Arow = (const f16x8*)&GF[kk][lj][0];
            f32x4 c = acc[kk][jtidx];
            c = __builtin_amdgcn_mfma_f32_16x16x32_f16(Arow[quad],     b0, c, 0, 0, 0);
            c = __builtin_amdgcn_mfma_f32_16x16x32_f16(Arow[4 + quad], b1, c, 0, 0, 0);
            c = __builtin_amdgcn_mfma_f32_16x16x32_f16(Arow[8 + quad], b2, c, 0, 0, 0);
            c = __builtin_amdgcn_mfma_f32_16x16x32_f16(((const f16x8*)&GT[kk][lj][0])[quad], b3, c, 0, 0, 0);
            acc[kk][jtidx] = c;
        }
    }

    // ---- select by adj + leaky_relu (C layout: col=lj, row=rbase+reg) ----
    float sel[4][4];
    #pragma unroll
    for (int jtidx = 0; jtidx < 4; ++jtidx) {
        const int j = (wave + 4 * jtidx) * 16 + lj;
        #pragma unroll
        for (int reg = 0; reg < 4; ++reg) {
            const int gi = i0 + rbase + reg;
            float s = NEGV;
            if (j < 200 && gi < 200) {
                const int k = adj[(size_t)(b * 200 + gi) * 200 + j];
                if (k >= 1 && k <= 4) {
                    const float v = (k == 1) ? acc[0][jtidx][reg]
                                  : (k == 2) ? acc[1][jtidx][reg]
                                  : (k == 3) ? acc[2][jtidx][reg]
                                  :            acc[3][jtidx][reg];
                    s = (v >= 0.f) ? v : SLOPE * v;
                }
            }
            sel[jtidx][reg] = s;
        }
    }

    // ---- softmax over j: wave-local butterflies + cross-wave LDS ----
    #pragma unroll
    for (int reg = 0; reg < 4; ++reg) {
        float m = fmaxf(fmaxf(sel[0][reg], sel[1][reg]), fmaxf(sel[2][reg], sel[3][reg]));
        #pragma unroll
        for (int off = 1; off <= 8; off <<= 1) m = fmaxf(m, __shfl_xor(m, off, 16));
        if (lj == 0) redmax[rbase + reg][wave] = m;
    }
    __syncthreads();
    float m4[4], lsum[4];
    #pragma unroll
    for (int reg = 0; reg < 4; ++reg) {
        const float* rr = redmax[rbase + reg];
        m4[reg] = fmaxf(fmaxf(rr[0], rr[1]), fmaxf(rr[2], rr[3]));
        lsum[reg] = 0.f;
    }
    float e[4][4];
    #pragma unroll
    for (int jtidx = 0; jtidx < 4; ++jtidx)
        #pragma unroll
        for (int reg = 0; reg < 4; ++reg) {
            e[jtidx][reg] = __expf(sel[jtidx][reg] - m4[reg]);
            lsum[reg] += e[jtidx][reg];
        }
    #pragma unroll
    for (int reg = 0; reg < 4; ++reg) {
        float s = lsum[reg];
        #pragma unroll
        for (int off = 1; off <= 8; off <<= 1) s += __shfl_xor(s, off, 16);
        if (lj == 0) redsum[rbase + reg][wave] = s;
    }
    __syncthreads();
    float inv[4];
    #pragma unroll
    for (int reg = 0; reg < 4; ++reg) {
        const float* rr = redsum[rbase + reg];
        inv[reg] = 1.0f / (rr[0] + rr[1] + rr[2] + rr[3]);
    }
    // GF is dead past this barrier -> write alpha into ST overlay
    #pragma unroll
    for (int jtidx = 0; jtidx < 4; ++jtidx) {
        const int j = (wave + 4 * jtidx) * 16 + lj;
        if (j < 200) {
            #pragma unroll
            for (int reg = 0; reg < 4; ++reg)
                ST[j][rbase + reg] = (f16)(e[jtidx][reg] * inv[reg]);
        }
    }
    __syncthreads();

    // ---- PV: thread (ig = tid&7 j-segment, dq = tid>>3 d-chunk of 4) ----
    const int ig = tid & 7;
    const int dq = tid >> 3;            // 0..31, active < 25
    f32x4 o[16];
    #pragma unroll
    for (int i = 0; i < 16; ++i) o[i] = (f32x4){0.f, 0.f, 0.f, 0.f};
    if (dq < 25) {
        for (int jj = 0; jj < 25; ++jj) {
            const int j = ig * 25 + jj;
            const f16x8 w0 = *(const f16x8*)&ST[j][0];
            const f16x8 w1 = *(const f16x8*)&ST[j][8];
            const f16x4 hv = *(const f16x4*)&HF[j][dq * 4];
            const float h0 = (float)hv[0], h1 = (float)hv[1],
                        h2 = (float)hv[2], h3 = (float)hv[3];
            #pragma unroll
            for (int i = 0; i < 8; ++i) {
                const float w = (float)w0[i];
                o[i][0] += w * h0; o[i][1] += w * h1; o[i][2] += w * h2; o[i][3] += w * h3;
            }
            #pragma unroll
            for (int i = 0; i < 8; ++i) {
                const float w = (float)w1[i];
                o[8 + i][0] += w * h0; o[8 + i][1] += w * h1; o[8 + i][2] += w * h2; o[8 + i][3] += w * h3;
            }
        }
    }
    #pragma unroll
    for (int i = 0; i < 16; ++i)
        #pragma unroll
        for (int c = 0; c < 4; ++c)
            #pragma unroll
            for (int off = 1; off <= 4; off <<= 1)
                o[i][c] += __shfl_xor(o[i][c], off, 8);
    if (ig == 0 && dq < 25) {
        #pragma unroll
        for (int i = 0; i < 16; ++i) {
            const int gi = i0 + i;
            if (gi < 200)
                ((f32x4*)out)[(size_t)(b * 200 + gi) * 25 + dq] = o[i];
        }
    }
}

extern "C" void kernel_launch(void* const* d_in, const int* in_sizes, int n_in,
                              void* d_out, int out_size, void* d_ws, size_t ws_size,
                              hipStream_t stream) {
    const int*   inputs = (const int*)  d_in[0];
    const int*   adj    = (const int*)  d_in[1];
    // d_in[2] = mask_item (all ones, unused)
    const float* emb    = (const float*)d_in[3];
    const float* a0     = (const float*)d_in[4];
    const float* a1     = (const float*)d_in[5];
    const float* a2     = (const float*)d_in[6];
    const float* a3     = (const float*)d_in[7];
    float*       out    = (float*)d_out;

    gat_mfma_kernel<<<dim3(32 * 13), dim3(256), 0, stream>>>(inputs, adj, emb, a0, a1, a2, a3, out);
}